// Round 4
// baseline (434.559 us; speedup 1.0000x reference)
//
#include <hip/hip_runtime.h>

#define B_N 131072
#define IN_N 40
#define H_N 256

typedef __bf16 bf16x8 __attribute__((ext_vector_type(8)));
typedef float f32x16 __attribute__((ext_vector_type(16)));

#define MFMA32(a, b, c) __builtin_amdgcn_mfma_f32_32x32x16_bf16(a, b, c, 0, 0, 0)

// ws layout (bf16 elements):
//   [0, 36864)        Wfused = W_ih @ W_proj  [768][48]  (cols 40..47 zero)
//   [36864, 233472)   W_hh   [768][256]
//   then f32 bfused[768] = b_ih + W_ih @ b_proj   (byte-aligned: offset*2 % 4 == 0)
#define WSF 0
#define WSH (768 * 48)
#define WSB_BF16IDX (768 * 48 + 768 * 256)
#define PREP_N (768 * 48 + 768 * 256 + 768 + B_N)

__global__ void prep(const float* __restrict__ Wp, const float* __restrict__ bp,
                     const float* __restrict__ Wih, const float* __restrict__ Whh,
                     const float* __restrict__ bih, const float* __restrict__ bhead,
                     __bf16* __restrict__ wsb, float* __restrict__ out) {
  int i = blockIdx.x * 256 + threadIdx.x;
  if (i < 768 * 48) {
    int g = i / 48, kk = i % 48;
    float v = 0.f;
    if (kk < IN_N) {
      for (int p = 0; p < 128; ++p) v += Wih[g * 128 + p] * Wp[p * IN_N + kk];
    }
    wsb[i] = (__bf16)v;
  } else if (i < WSB_BF16IDX) {
    wsb[i] = (__bf16)Whh[i - WSH];
  } else if (i < WSB_BF16IDX + 768) {
    int g = i - WSB_BF16IDX;
    float v = bih[g];
    for (int p = 0; p < 128; ++p) v += Wih[g * 128 + p] * bp[p];
    ((float*)(wsb + WSB_BF16IDX))[g] = v;
  } else if (i < PREP_N) {
    out[i - (WSB_BF16IDX + 768)] = bhead[0];  // pred init = bias; waves atomicAdd
  }
}

__device__ __forceinline__ bf16x8 cvt8(float4 a, float4 b) {
  bf16x8 r;
  r[0] = (__bf16)a.x; r[1] = (__bf16)a.y; r[2] = (__bf16)a.z; r[3] = (__bf16)a.w;
  r[4] = (__bf16)b.x; r[5] = (__bf16)b.y; r[6] = (__bf16)b.z; r[7] = (__bf16)b.w;
  return r;
}

// 256 thr = 4 waves, block = 64 rows x 64 cols, wave = 32 rows x 32 cols.
// No LDS, no barriers: A-frags straight from global (f32 -> bf16 in reg),
// B-frags from bf16 weights in ws (L2-hot).
__global__ __launch_bounds__(256, 3) void gru_v5(
    const float* __restrict__ x, const float* __restrict__ h0,
    const __bf16* __restrict__ wsb, const float* __restrict__ bhh,
    const float* __restrict__ Whead, float* __restrict__ out) {
  const int tid = threadIdx.x;
  // XCD swizzle: 4 col-siblings + sequential row tiles adjacent on one XCD
  const int t = (blockIdx.x & 7) * 1024 + (blockIdx.x >> 3);
  const int ch = t & 3;                 // column quarter (64 cols)
  const int rowbase = (t >> 2) * 64;
  const int lane = tid & 63;
  const int w = tid >> 6;
  const int wr = w >> 1, wc = w & 1;    // wave row-half / col-half
  const int l31 = lane & 31;
  const int kh = lane >> 5;             // k-half of the fragment
  const int grow0 = rowbase + wr * 32 + l31;  // this lane's A row
  const int col = ch * 64 + wc * 32 + l31;    // this lane's output H col

  const float* bfused = (const float*)(wsb + WSB_BF16IDX);
  f32x16 aR, aZ, aIN, aHN;
  {
    const float vR = bfused[col] + bhh[col];
    const float vZ = bfused[H_N + col] + bhh[H_N + col];
    const float vI = bfused[2 * H_N + col];
    const float vH = bhh[2 * H_N + col];
#pragma unroll
    for (int r = 0; r < 16; ++r) {
      aR[r] = vR; aZ[r] = vZ; aIN[r] = vI; aHN[r] = vH;
    }
  }

  // ---- gi: K=48 (x, fused weights), 3 k-steps ----
  const __bf16* WF = wsb + WSF;
  {
    const float* xr = x + (size_t)grow0 * IN_N;
#pragma unroll
    for (int ks = 0; ks < 3; ++ks) {
      // ks==2, kh==1 would read x[40..47] (OOB): clamp to 32 — its B cols are zero.
      const int ko = (ks * 16 + kh * 8 <= 32) ? ks * 16 + kh * 8 : 32;
      float4 a0 = *reinterpret_cast<const float4*>(xr + ko);
      float4 a1 = *reinterpret_cast<const float4*>(xr + ko + 4);
      bf16x8 af = cvt8(a0, a1);
      const int kb = ks * 16 + kh * 8;
      bf16x8 bR = *reinterpret_cast<const bf16x8*>(WF + (size_t)(col) * 48 + kb);
      bf16x8 bZ = *reinterpret_cast<const bf16x8*>(WF + (size_t)(H_N + col) * 48 + kb);
      bf16x8 bN = *reinterpret_cast<const bf16x8*>(WF + (size_t)(2 * H_N + col) * 48 + kb);
      aR = MFMA32(af, bR, aR);
      aZ = MFMA32(af, bZ, aZ);
      aIN = MFMA32(af, bN, aIN);
    }
  }
  // ---- gh: K=256 (h, W_hh), 16 k-steps ----
  const __bf16* WH = wsb + WSH;
  {
    const float* hr = h0 + (size_t)grow0 * H_N;
#pragma unroll
    for (int ks = 0; ks < 16; ++ks) {
      const int ko = ks * 16 + kh * 8;
      float4 a0 = *reinterpret_cast<const float4*>(hr + ko);
      float4 a1 = *reinterpret_cast<const float4*>(hr + ko + 4);
      bf16x8 af = cvt8(a0, a1);
      bf16x8 bR = *reinterpret_cast<const bf16x8*>(WH + (size_t)(col) * 256 + ko);
      bf16x8 bZ = *reinterpret_cast<const bf16x8*>(WH + (size_t)(H_N + col) * 256 + ko);
      bf16x8 bN = *reinterpret_cast<const bf16x8*>(WH + (size_t)(2 * H_N + col) * 256 + ko);
      aR = MFMA32(af, bR, aR);
      aZ = MFMA32(af, bZ, aZ);
      aHN = MFMA32(af, bN, aHN);
    }
  }

  // ---- epilogue: gates (f32), h_new store, pred partials ----
  const float wh = Whead[col];
  float ps[16];
#pragma unroll
  for (int r = 0; r < 16; ++r) {
    const int rl = (r & 3) + 8 * (r >> 2) + 4 * kh;  // C/D row mapping (m74/m101)
    const size_t grow = (size_t)(rowbase + wr * 32 + rl);
    const float rg = 1.f / (1.f + __expf(-aR[r]));
    const float zg = 1.f / (1.f + __expf(-aZ[r]));
    const float e2 = __expf(2.f * (aIN[r] + rg * aHN[r]));
    const float ng = (e2 - 1.f) / (e2 + 1.f);
    const float hv = h0[grow * H_N + col];
    const float hn = (1.f - zg) * ng + zg * hv;
    out[(size_t)B_N + grow * H_N + col] = hn;
    ps[r] = hn * wh;
  }
  // reduce pred partial over the wave's 32 cols (lanes within each half)
#pragma unroll
  for (int r = 0; r < 16; ++r) {
    float s = ps[r];
    s += __shfl_xor(s, 1);
    s += __shfl_xor(s, 2);
    s += __shfl_xor(s, 4);
    s += __shfl_xor(s, 8);
    s += __shfl_xor(s, 16);
    ps[r] = s;
  }
  if (l31 == 0) {  // lanes 0 and 32: 32 distinct rows
#pragma unroll
    for (int r = 0; r < 16; ++r) {
      const int rl = (r & 3) + 8 * (r >> 2) + 4 * kh;
      atomicAdd(&out[rowbase + wr * 32 + rl], ps[r]);
    }
  }
}

extern "C" void kernel_launch(void* const* d_in, const int* in_sizes, int n_in,
                              void* d_out, int out_size, void* d_ws, size_t ws_size,
                              hipStream_t stream) {
  const float* x     = (const float*)d_in[0];
  const float* h0    = (const float*)d_in[1];
  const float* Wp    = (const float*)d_in[2];
  const float* bp    = (const float*)d_in[3];
  const float* Wih   = (const float*)d_in[4];
  const float* Whh   = (const float*)d_in[5];
  const float* bih   = (const float*)d_in[6];
  const float* bhh   = (const float*)d_in[7];
  const float* Whead = (const float*)d_in[8];
  const float* bhead = (const float*)d_in[9];
  float* out = (float*)d_out;
  __bf16* wsb = (__bf16*)d_ws;

  prep<<<(PREP_N + 255) / 256, 256, 0, stream>>>(Wp, bp, Wih, Whh, bih, bhead, wsb, out);
  gru_v5<<<(B_N / 64) * 4, 256, 0, stream>>>(x, h0, wsb, bhh, Whead, out);
}

// Round 5
// 216.165 us; speedup vs baseline: 2.0103x; 2.0103x over previous
//
#include <hip/hip_runtime.h>

#define B_N 131072
#define IN_N 40
#define H_N 256

typedef __bf16 bf16x8 __attribute__((ext_vector_type(8)));
typedef __bf16 bf16x4 __attribute__((ext_vector_type(4)));
typedef float f32x4 __attribute__((ext_vector_type(4)));

#define MFMA(a, b, c) __builtin_amdgcn_mfma_f32_16x16x32_bf16(a, b, c, 0, 0, 0)

// ws layout (bf16 elements):
//   [0, 49152)        Wfused = W_ih @ W_proj  [768][64]  (cols 40..63 zero)
//   [49152, 245760)   W_hh   [768][256]
//   [245760, +1536)   bfused f32[768] = b_ih + W_ih @ b_proj
#define WSF 0
#define WSH 49152
#define WSBI 245760
#define PREP_N (245760 + 768 + B_N)

__global__ void prep(const float* __restrict__ Wp, const float* __restrict__ bp,
                     const float* __restrict__ Wih, const float* __restrict__ Whh,
                     const float* __restrict__ bih, const float* __restrict__ bhead,
                     __bf16* __restrict__ wsb, float* __restrict__ out) {
  int i = blockIdx.x * 256 + threadIdx.x;
  if (i < WSH) {
    int g = i >> 6, kk = i & 63;
    float v = 0.f;
    if (kk < IN_N) {
      for (int p = 0; p < 128; ++p) v += Wih[g * 128 + p] * Wp[p * IN_N + kk];
    }
    wsb[i] = (__bf16)v;
  } else if (i < WSBI) {
    wsb[i] = (__bf16)Whh[i - WSH];
  } else if (i < WSBI + 768) {
    int g = i - WSBI;
    float v = bih[g];
    for (int p = 0; p < 128; ++p) v += Wih[g * 128 + p] * bp[p];
    ((float*)(wsb + WSBI))[g] = v;
  } else if (i < PREP_N) {
    out[i - (WSBI + 768)] = bhead[0];  // pred init = bias; waves atomicAdd partials
  }
}

// 512 thr = 8 waves, 1 block/CU (LDS 84KB, VGPR~230). Wave owns 16 H-cols,
// block covers a 128-col half; loops over 8 row-tiles of 64 with
// double-buffered LDS staging. Weights live in VGPRs for the whole kernel.
__global__ __launch_bounds__(512, 2) void gru_v6(
    const float* __restrict__ x, const float* __restrict__ h0,
    const __bf16* __restrict__ wsb, const float* __restrict__ bhh,
    const float* __restrict__ Whead, float* __restrict__ out) {
  __shared__ __bf16 hs[2][64][264];   // stride 264: b128 reads spread quads evenly
  __shared__ __bf16 xs[2][64][72];

  const int tid = threadIdx.x;
  const int lane = tid & 63;
  const int w = tid >> 6;
  const int l15 = lane & 15;
  const int l4 = lane >> 4;
  const int koff = l4 * 8;

  // XCD-chunked swizzle: col-half pair + consecutive segs share an XCD (L2 h reuse)
  const int b = blockIdx.x;
  const int v = (b & 7) * 64 + (b >> 3);
  const int half = v & 1;
  const int tile0 = (v >> 1) * 8;
  const int col = half * 128 + w * 16 + l15;

  // ---- load weights into registers (once) ----
  const __bf16* WH = wsb + WSH;
  const __bf16* WF = wsb + WSF;
  bf16x8 whR[8], whZ[8], whN[8], wfR[2], wfZ[2], wfN[2];
#pragma unroll
  for (int ks = 0; ks < 8; ++ks) {
    const int k = ks * 32 + koff;
    whR[ks] = *reinterpret_cast<const bf16x8*>(WH + (size_t)col * 256 + k);
    whZ[ks] = *reinterpret_cast<const bf16x8*>(WH + (size_t)(256 + col) * 256 + k);
    whN[ks] = *reinterpret_cast<const bf16x8*>(WH + (size_t)(512 + col) * 256 + k);
  }
#pragma unroll
  for (int ks = 0; ks < 2; ++ks) {
    const int k = ks * 32 + koff;
    wfR[ks] = *reinterpret_cast<const bf16x8*>(WF + (size_t)col * 64 + k);
    wfZ[ks] = *reinterpret_cast<const bf16x8*>(WF + (size_t)(256 + col) * 64 + k);
    wfN[ks] = *reinterpret_cast<const bf16x8*>(WF + (size_t)(512 + col) * 64 + k);
  }
  const float* bfused = (const float*)(wsb + WSBI);
  const float bR = bfused[col] + bhh[col];
  const float bZ = bfused[256 + col] + bhh[256 + col];
  const float bI = bfused[512 + col];
  const float bH = bhh[512 + col];
  const float whead = Whead[col];

  auto stage = [&](int buf, int row0) {
    const float* hb = h0 + (size_t)row0 * H_N;
#pragma unroll
    for (int j = 0; j < 8; ++j) {
      const int flat = (tid + j * 512) * 4;
      const int r = flat >> 8, c = flat & 255;
      float4 vv = *reinterpret_cast<const float4*>(hb + flat);
      bf16x4 u;
      u[0] = (__bf16)vv.x; u[1] = (__bf16)vv.y; u[2] = (__bf16)vv.z; u[3] = (__bf16)vv.w;
      *reinterpret_cast<bf16x4*>(&hs[buf][r][c]) = u;
    }
    const float* xb = x + (size_t)row0 * IN_N;
#pragma unroll
    for (int j = 0; j < 5; ++j) {
      const int i = tid + j * 512;
      xs[buf][i / 40][i % 40] = (__bf16)xb[i];
    }
#pragma unroll
    for (int j = 0; j < 3; ++j) {
      const int i = tid + j * 512;
      xs[buf][i / 24][40 + i % 24] = (__bf16)0.f;
    }
  };

  stage(0, tile0 * 64);
  __syncthreads();

  for (int t = 0; t < 8; ++t) {
    const int cur = t & 1;
    const int row0 = (tile0 + t) * 64;
    if (t < 7) stage(cur ^ 1, row0 + 64);

    f32x4 aR[4], aZ[4], aI[4], aH[4];
#pragma unroll
    for (int mi = 0; mi < 4; ++mi) {
      aR[mi] = (f32x4){bR, bR, bR, bR};
      aZ[mi] = (f32x4){bZ, bZ, bZ, bZ};
      aI[mi] = (f32x4){bI, bI, bI, bI};
      aH[mi] = (f32x4){bH, bH, bH, bH};
    }
    // gi: K=64 (padded) over xs, weights in regs
#pragma unroll
    for (int ks = 0; ks < 2; ++ks) {
#pragma unroll
      for (int mi = 0; mi < 4; ++mi) {
        const bf16x8 a = *reinterpret_cast<const bf16x8*>(&xs[cur][mi * 16 + l15][ks * 32 + koff]);
        aR[mi] = MFMA(a, wfR[ks], aR[mi]);
        aZ[mi] = MFMA(a, wfZ[ks], aZ[mi]);
        aI[mi] = MFMA(a, wfN[ks], aI[mi]);
      }
    }
    // gh: K=256 over hs, weights in regs
#pragma unroll
    for (int ks = 0; ks < 8; ++ks) {
#pragma unroll
      for (int mi = 0; mi < 4; ++mi) {
        const bf16x8 a = *reinterpret_cast<const bf16x8*>(&hs[cur][mi * 16 + l15][ks * 32 + koff]);
        aR[mi] = MFMA(a, whR[ks], aR[mi]);
        aZ[mi] = MFMA(a, whZ[ks], aZ[mi]);
        aH[mi] = MFMA(a, whN[ks], aH[mi]);
      }
    }
    // epilogue
    float ps[4][4];
#pragma unroll
    for (int mi = 0; mi < 4; ++mi) {
#pragma unroll
      for (int r = 0; r < 4; ++r) {
        const int row = mi * 16 + l4 * 4 + r;
        const float rg = 1.f / (1.f + __expf(-aR[mi][r]));
        const float zg = 1.f / (1.f + __expf(-aZ[mi][r]));
        const float e2 = __expf(2.f * (aI[mi][r] + rg * aH[mi][r]));
        const float ng = (e2 - 1.f) / (e2 + 1.f);
        const float hv = (float)hs[cur][row][col];
        const float hn = (1.f - zg) * ng + zg * hv;
        out[(size_t)B_N + (size_t)(row0 + row) * H_N + col] = hn;
        ps[mi][r] = hn * whead;
      }
    }
#pragma unroll
    for (int mi = 0; mi < 4; ++mi)
#pragma unroll
      for (int r = 0; r < 4; ++r) {
        float s = ps[mi][r];
        s += __shfl_xor(s, 1);
        s += __shfl_xor(s, 2);
        s += __shfl_xor(s, 4);
        s += __shfl_xor(s, 8);
        if (l15 == 0) atomicAdd(&out[row0 + mi * 16 + l4 * 4 + r], s);
      }
    __syncthreads();
  }
}

extern "C" void kernel_launch(void* const* d_in, const int* in_sizes, int n_in,
                              void* d_out, int out_size, void* d_ws, size_t ws_size,
                              hipStream_t stream) {
  const float* x     = (const float*)d_in[0];
  const float* h0    = (const float*)d_in[1];
  const float* Wp    = (const float*)d_in[2];
  const float* bp    = (const float*)d_in[3];
  const float* Wih   = (const float*)d_in[4];
  const float* Whh   = (const float*)d_in[5];
  const float* bih   = (const float*)d_in[6];
  const float* bhh   = (const float*)d_in[7];
  const float* Whead = (const float*)d_in[8];
  const float* bhead = (const float*)d_in[9];
  float* out = (float*)d_out;
  __bf16* wsb = (__bf16*)d_ws;

  prep<<<(PREP_N + 255) / 256, 256, 0, stream>>>(Wp, bp, Wih, Whh, bih, bhead, wsb, out);
  gru_v6<<<512, 512, 0, stream>>>(x, h0, wsb, bhh, Whead, out);
}